// Round 8
// baseline (1483.960 us; speedup 1.0000x reference)
//
#include <hip/hip_runtime.h>
#include <math.h>

#define NN 50000
#define HH 256
#define FIN 128
#define CC 112
#define LL 8
#define EE 800000
#define EPSB 1e-5f
#define NGRP 8
#define NPG (NN / NGRP)     // 6250 nodes per XCD-group
#define SLW 32              // spmm column-slice width (u16 -> 64 B/row = 1 line)
#define NSL (HH / SLW)      // 8 slices, one per XCD
#define BCAP 110000         // bucket capacity (Binomial(800k,1/8): mean 100k, +33 sigma)

typedef unsigned short u16;
typedef unsigned int u32;
typedef __attribute__((ext_vector_type(8))) short bf16x8;
typedef __attribute__((ext_vector_type(4))) float f32x4;

__device__ __forceinline__ u16 f2bf(float f) {
    u32 u = __float_as_uint(f);
    u32 r = (u + 0x7FFFu + ((u >> 16) & 1u)) >> 16;   // RNE
    return (u16)r;
}
__device__ __forceinline__ float bflo(u32 u) { return __uint_as_float(u << 16); }
__device__ __forceinline__ float bfhi(u32 u) { return __uint_as_float(u & 0xFFFF0000u); }
__device__ __forceinline__ float bf1(u16 u) { return __uint_as_float(((u32)u) << 16); }

__device__ __forceinline__ void gload16(const u16* g, u16* l) {
    __builtin_amdgcn_global_load_lds(
        (const __attribute__((address_space(1))) void*)g,
        (__attribute__((address_space(3))) void*)l, 16, 0, 0);
}

// ---------------- CSR build pass A: partition edges into 16 buckets --------------------------
__global__ __launch_bounds__(256) void k_part(const int* __restrict__ ed1,
                                              const int* __restrict__ ed2,
                                              int* __restrict__ bcnt,
                                              u32* __restrict__ bucket) {
    __shared__ int hist[16], base[16], cnt2[16];
    const int t = threadIdx.x;
    if (t < 16) { hist[t] = 0; cnt2[t] = 0; }
    __syncthreads();
    const int e0 = blockIdx.x * 2048;
    int myb[8]; u32 myp[8];
#pragma unroll
    for (int k = 0; k < 8; ++k) {
        int e = e0 + k * 256 + t;
        myb[k] = -1;
        if (e < 2 * EE) {
            const int* ed = (e < EE) ? ed1 : ed2;
            int ee = (e < EE) ? e : e - EE;
            int c = ed[ee + EE];
            int r = ed[ee];
            int b = ((e >= EE) ? 8 : 0) | (c / NPG);
            myb[k] = b;
            myp[k] = ((u32)c << 16) | (u32)r;
            atomicAdd(&hist[b], 1);
        }
    }
    __syncthreads();
    if (t < 16) base[t] = atomicAdd(&bcnt[t], hist[t]);
    __syncthreads();
#pragma unroll
    for (int k = 0; k < 8; ++k) {
        if (myb[k] >= 0) {
            int off = atomicAdd(&cnt2[myb[k]], 1);
            bucket[(size_t)myb[k] * BCAP + base[myb[k]] + off] = myp[k];
        }
    }
}

// ---------------- CSR build pass B: per-XCD scatter from own bucket --------------------------
__global__ __launch_bounds__(256) void k_fillB(const u32* __restrict__ bucket,
                                               const int* __restrict__ bcnt,
                                               int* __restrict__ cur,
                                               u16* __restrict__ src1p,
                                               u16* __restrict__ src2p) {
    const int b = blockIdx.x & 15;
    const int n = bcnt[b];
    u16* sp = (b < 8) ? src1p : src2p;
    int* cu = (b < 8) ? cur : cur + NN;
    const u32* bk = bucket + (size_t)b * BCAP;
    const int stride = (gridDim.x >> 4) * 256;
    for (int i = (blockIdx.x >> 4) * 256 + threadIdx.x; i < n; i += stride) {
        u32 p = bk[i];
        int c = p >> 16;
        int r = p & 0xFFFFu;
        int pos = atomicAdd(&cu[c], 1);
        sp[(c << 6) + pos] = (u16)r;
    }
}

// dinv + degree histogram (64 bins per graph) for the counting sort
__global__ void k_dinv2(const int* __restrict__ deg, float* __restrict__ dinv1,
                        float* __restrict__ dinv2, int* __restrict__ hist, int n) {
    int v = blockIdx.x * blockDim.x + threadIdx.x;
    if (v >= 2 * n) return;
    float* d = (v < n) ? dinv1 : dinv2;
    int vv = (v < n) ? v : v - n;
    int dg = deg[v];
    d[vv] = rsqrtf((float)(dg + 1));  // +1 self-loop
    int bin = dg > 63 ? 63 : dg;
    atomicAdd(&hist[((v >= n) ? 64 : 0) + bin], 1);
}

// exclusive prefix over the 64 degree bins of each graph (tiny)
__global__ void k_dscan(const int* __restrict__ hist, int* __restrict__ off) {
    int g = threadIdx.x;
    if (g >= 2) return;
    int s = 0;
    for (int d = 0; d < 64; ++d) { off[g * 64 + d] = s; s += hist[g * 64 + d]; }
}

// place nodes into degree-sorted perm arrays (order within a bin arbitrary)
__global__ void k_dplace(const int* __restrict__ deg, int* __restrict__ off,
                         u16* __restrict__ perm1, u16* __restrict__ perm2, int n) {
    int v = blockIdx.x * blockDim.x + threadIdx.x;
    if (v >= 2 * n) return;
    int g = (v >= n) ? 1 : 0;
    int vv = g ? v - n : v;
    int dg = deg[v];
    int bin = dg > 63 ? 63 : dg;
    int pos = atomicAdd(&off[g * 64 + bin], 1);
    (g ? perm2 : perm1)[pos] = (u16)vv;
}

// ---------------- weight transpose + bf16 cast: W[K][N] f32 -> Wt[N][K] bf16 ----------------
__global__ void k_wt(const float* __restrict__ W, u16* __restrict__ Wt, int K, int N) {
    __shared__ u16 sm[32][33];
    const float* Wl = W + (size_t)blockIdx.z * K * N;
    u16* Wtl = Wt + (size_t)blockIdx.z * K * N;
    int k0 = blockIdx.y * 32, n0 = blockIdx.x * 32;
    int tx = threadIdx.x, ty = threadIdx.y;  // 32 x 8
#pragma unroll
    for (int r = 0; r < 32; r += 8)
        sm[ty + r][tx] = f2bf(Wl[(size_t)(k0 + ty + r) * N + n0 + tx]);
    __syncthreads();
#pragma unroll
    for (int r = 0; r < 32; r += 8)
        Wtl[(size_t)(n0 + ty + r) * K + k0 + tx] = sm[tx][ty + r];
}

// outW [H=256][C=112] f32 -> outWt [128][256] bf16 (rows >= C zero); pad bias to 128
__global__ void k_outwt(const float* __restrict__ outW, const float* __restrict__ outb,
                        u16* __restrict__ outWt, float* __restrict__ obb) {
    int idx = blockIdx.x * 256 + threadIdx.x;     // 128*256
    if (idx >= 128 * 256) return;
    int n = idx >> 8, k = idx & 255;
    float v = (n < CC) ? outW[(size_t)k * CC + n] : 0.f;
    outWt[(size_t)n * HH + k] = f2bf(v);
    if (idx < 128) obb[idx] = (idx < CC) ? outb[idx] : 0.f;
}

// ---------------- fp32 -> bf16 cast ----------------
__global__ void k_xcast(const float* __restrict__ x, u16* __restrict__ xb, int n4) {
    int i = blockIdx.x * blockDim.x + threadIdx.x;
    if (i >= n4) return;
    float4 v = ((const float4*)x)[i];
    ushort4 o;
    o.x = f2bf(v.x); o.y = f2bf(v.y); o.z = f2bf(v.z); o.w = f2bf(v.w);
    *(ushort4*)(xb + ((size_t)i << 2)) = o;
}

// ---- bf16 MFMA GEMM: C = A @ Bt^T + bias, per-row scale; XCD-aware m/n swizzle when SWIZ ---
// SLICED: store u16 C in column-sliced layout [Nc/32][M][32] for the L2-pinned spmm gather.
template <bool F32OUT, bool SWIZ, bool SLICED>
__global__ __launch_bounds__(256) void k_gemm_bf16(const u16* __restrict__ A,
                                                   const u16* __restrict__ Bt,
                                                   const float* __restrict__ bias,
                                                   const float* __restrict__ rowscale,
                                                   void* __restrict__ Cout,
                                                   int M, int Nc, int K) {
    int m0, n0;
    if (SWIZ) {
        int id = blockIdx.x;
        int g = id >> 4, r = id & 15;
        int m = g * 8 + (r & 7);
        if (m * 128 >= M) return;
        m0 = m * 128;
        n0 = (r >> 3) * 128;
    } else {
        m0 = blockIdx.x * 128;
        n0 = 0;
    }
    __shared__ u16 As[128 * 32];
    __shared__ u16 Bs[128 * 32];
    const int tid = threadIdx.x;
    const int w = tid >> 6, lane = tid & 63;
    const int wr = (w >> 1) * 64, wc = (w & 1) * 64;
    const int lm = lane & 15, lq = lane >> 4;

    f32x4 acc[4][4];
#pragma unroll
    for (int i = 0; i < 4; ++i)
#pragma unroll
        for (int j = 0; j < 4; ++j) acc[i][j] = (f32x4){0.f, 0.f, 0.f, 0.f};

    const int srow = w * 16 + (lane >> 2);
    const int scol = (lane & 3) * 8;

    for (int k0 = 0; k0 < K; k0 += 32) {
        int gm = m0 + srow;        if (gm >= M) gm = M - 1;
        gload16(A + (size_t)gm * K + k0 + scol, As + (size_t)(w * 64) * 8);
        int gm2 = m0 + 64 + srow;  if (gm2 >= M) gm2 = M - 1;
        gload16(A + (size_t)gm2 * K + k0 + scol, As + (size_t)(256 + w * 64) * 8);
        gload16(Bt + (size_t)(n0 + srow) * K + k0 + scol, Bs + (size_t)(w * 64) * 8);
        gload16(Bt + (size_t)(n0 + 64 + srow) * K + k0 + scol, Bs + (size_t)(256 + w * 64) * 8);
        __syncthreads();

        bf16x8 af[4], bfr[4];
#pragma unroll
        for (int i = 0; i < 4; ++i)
            af[i] = *(const bf16x8*)(As + (wr + i * 16 + lm) * 32 + lq * 8);
#pragma unroll
        for (int j = 0; j < 4; ++j)
            bfr[j] = *(const bf16x8*)(Bs + (wc + j * 16 + lm) * 32 + lq * 8);
#pragma unroll
        for (int i = 0; i < 4; ++i)
#pragma unroll
            for (int j = 0; j < 4; ++j)
                acc[i][j] = __builtin_amdgcn_mfma_f32_16x16x32_bf16(af[i], bfr[j], acc[i][j], 0, 0, 0);
        __syncthreads();
    }

    // epilogue: C/D layout col=lane&15, row=(lane>>4)*4+reg  [m89-verified]
#pragma unroll
    for (int j = 0; j < 4; ++j) {
        int gc = n0 + wc + j * 16 + lm;
        float bj = (gc < Nc) ? bias[gc] : 0.f;
#pragma unroll
        for (int i = 0; i < 4; ++i) {
#pragma unroll
            for (int r = 0; r < 4; ++r) {
                int gr = m0 + wr + i * 16 + lq * 4 + r;
                if (gr < M && gc < Nc) {
                    float rs = rowscale ? rowscale[gr] : 1.0f;
                    float val = (acc[i][j][r] + bj) * rs;
                    if (F32OUT)
                        ((float*)Cout)[(size_t)gr * Nc + gc] = val;
                    else if (SLICED)
                        ((u16*)Cout)[((size_t)(gc >> 5) * M + gr) * SLW + (gc & 31)] = f2bf(val);
                    else
                        ((u16*)Cout)[(size_t)gr * Nc + gc] = f2bf(val);
                }
            }
        }
    }
}

// -- column-sliced gather SpMM, 8-lane row-subgroups, DEGREE-SORTED node order ---------------
// Round-7 diagnosis: VALU floor = E*H adds + equal unpacks ~43 us/layer; observed 68 =
// 43 x 1.5 divergence inflation (8 iid Poisson(16) degrees per wave -> exec-masked loop runs
// E[max]=24 vs mean 16). Fix: v = perm[vi] with perm degree-sorted -> 8 consecutive nodes
// have deg within +-1 -> uniform trip counts. hpre node-slice write is one full 64 B line,
// so the scattered write order adds nothing.
__global__ __launch_bounds__(512) void k_spmm_sl8(const u16* __restrict__ ts,
                                                  const int* __restrict__ deg,
                                                  const u16* __restrict__ srcp,
                                                  const float* __restrict__ dinv,
                                                  const u16* __restrict__ perm,
                                                  u16* __restrict__ hpre,
                                                  float* __restrict__ bns,   // [8][HH]
                                                  float* __restrict__ bnq) { // [8][HH]
    __shared__ float lsum[8][SLW];
    __shared__ float lsq[8][SLW];
    const int s = blockIdx.x & 7;
    const int nb = blockIdx.x >> 3;
    const int w = threadIdx.x >> 6;
    const int lane = threadIdx.x & 63;
    const int sub = lane >> 3;          // node subgroup 0..7
    const int li = lane & 7;            // lane covers cols 4li..4li+3 of the slice (uint2)
    const u16* tsl = ts + (size_t)s * NN * SLW + li * 4;

    const int vi = nb * 64 + w * 8 + sub;
    float4 ssum = make_float4(0.f, 0.f, 0.f, 0.f);
    float4 ssq  = make_float4(0.f, 0.f, 0.f, 0.f);

    if (vi < NN) {
        const int v = perm[vi];
        const u16* src = srcp + ((size_t)v << 6);
        const float dv = dinv[v];
        uint2 a = *(const uint2*)(tsl + (size_t)v * SLW);
        float4 A;
        A.x = bflo(a.x); A.y = bfhi(a.x); A.z = bflo(a.y); A.w = bfhi(a.y);
        int end = deg[v];
        int j = 0;
        for (; j + 16 <= end; j += 16) {
            uint4 sp0 = *(const uint4*)(src + j);
            uint4 sp1 = *(const uint4*)(src + j + 8);
            uint2 b0 = *(const uint2*)(tsl + (size_t)(sp0.x & 0xFFFFu) * SLW);
            uint2 b1 = *(const uint2*)(tsl + (size_t)(sp0.x >> 16) * SLW);
            uint2 b2 = *(const uint2*)(tsl + (size_t)(sp0.y & 0xFFFFu) * SLW);
            uint2 b3 = *(const uint2*)(tsl + (size_t)(sp0.y >> 16) * SLW);
            uint2 b4 = *(const uint2*)(tsl + (size_t)(sp0.z & 0xFFFFu) * SLW);
            uint2 b5 = *(const uint2*)(tsl + (size_t)(sp0.z >> 16) * SLW);
            uint2 b6 = *(const uint2*)(tsl + (size_t)(sp0.w & 0xFFFFu) * SLW);
            uint2 b7 = *(const uint2*)(tsl + (size_t)(sp0.w >> 16) * SLW);
            uint2 c0 = *(const uint2*)(tsl + (size_t)(sp1.x & 0xFFFFu) * SLW);
            uint2 c1 = *(const uint2*)(tsl + (size_t)(sp1.x >> 16) * SLW);
            uint2 c2 = *(const uint2*)(tsl + (size_t)(sp1.y & 0xFFFFu) * SLW);
            uint2 c3 = *(const uint2*)(tsl + (size_t)(sp1.y >> 16) * SLW);
            uint2 c4 = *(const uint2*)(tsl + (size_t)(sp1.z & 0xFFFFu) * SLW);
            uint2 c5 = *(const uint2*)(tsl + (size_t)(sp1.z >> 16) * SLW);
            uint2 c6 = *(const uint2*)(tsl + (size_t)(sp1.w & 0xFFFFu) * SLW);
            uint2 c7 = *(const uint2*)(tsl + (size_t)(sp1.w >> 16) * SLW);
            A.x += bflo(b0.x) + bflo(b1.x) + bflo(b2.x) + bflo(b3.x)
                 + bflo(b4.x) + bflo(b5.x) + bflo(b6.x) + bflo(b7.x)
                 + bflo(c0.x) + bflo(c1.x) + bflo(c2.x) + bflo(c3.x)
                 + bflo(c4.x) + bflo(c5.x) + bflo(c6.x) + bflo(c7.x);
            A.y += bfhi(b0.x) + bfhi(b1.x) + bfhi(b2.x) + bfhi(b3.x)
                 + bfhi(b4.x) + bfhi(b5.x) + bfhi(b6.x) + bfhi(b7.x)
                 + bfhi(c0.x) + bfhi(c1.x) + bfhi(c2.x) + bfhi(c3.x)
                 + bfhi(c4.x) + bfhi(c5.x) + bfhi(c6.x) + bfhi(c7.x);
            A.z += bflo(b0.y) + bflo(b1.y) + bflo(b2.y) + bflo(b3.y)
                 + bflo(b4.y) + bflo(b5.y) + bflo(b6.y) + bflo(b7.y)
                 + bflo(c0.y) + bflo(c1.y) + bflo(c2.y) + bflo(c3.y)
                 + bflo(c4.y) + bflo(c5.y) + bflo(c6.y) + bflo(c7.y);
            A.w += bfhi(b0.y) + bfhi(b1.y) + bfhi(b2.y) + bfhi(b3.y)
                 + bfhi(b4.y) + bfhi(b5.y) + bfhi(b6.y) + bfhi(b7.y)
                 + bfhi(c0.y) + bfhi(c1.y) + bfhi(c2.y) + bfhi(c3.y)
                 + bfhi(c4.y) + bfhi(c5.y) + bfhi(c6.y) + bfhi(c7.y);
        }
        for (; j + 8 <= end; j += 8) {
            uint4 sp = *(const uint4*)(src + j);   // 8 packed u16 indices (subgroup-bcast)
            uint2 b0 = *(const uint2*)(tsl + (size_t)(sp.x & 0xFFFFu) * SLW);
            uint2 b1 = *(const uint2*)(tsl + (size_t)(sp.x >> 16) * SLW);
            uint2 b2 = *(const uint2*)(tsl + (size_t)(sp.y & 0xFFFFu) * SLW);
            uint2 b3 = *(const uint2*)(tsl + (size_t)(sp.y >> 16) * SLW);
            uint2 b4 = *(const uint2*)(tsl + (size_t)(sp.z & 0xFFFFu) * SLW);
            uint2 b5 = *(const uint2*)(tsl + (size_t)(sp.z >> 16) * SLW);
            uint2 b6 = *(const uint2*)(tsl + (size_t)(sp.w & 0xFFFFu) * SLW);
            uint2 b7 = *(const uint2*)(tsl + (size_t)(sp.w >> 16) * SLW);
            A.x += bflo(b0.x) + bflo(b1.x) + bflo(b2.x) + bflo(b3.x)
                 + bflo(b4.x) + bflo(b5.x) + bflo(b6.x) + bflo(b7.x);
            A.y += bfhi(b0.x) + bfhi(b1.x) + bfhi(b2.x) + bfhi(b3.x)
                 + bfhi(b4.x) + bfhi(b5.x) + bfhi(b6.x) + bfhi(b7.x);
            A.z += bflo(b0.y) + bflo(b1.y) + bflo(b2.y) + bflo(b3.y)
                 + bflo(b4.y) + bflo(b5.y) + bflo(b6.y) + bflo(b7.y);
            A.w += bfhi(b0.y) + bfhi(b1.y) + bfhi(b2.y) + bfhi(b3.y)
                 + bfhi(b4.y) + bfhi(b5.y) + bfhi(b6.y) + bfhi(b7.y);
        }
        for (; j + 2 <= end; j += 2) {
            int s0 = src[j], s1 = src[j + 1];
            uint2 b0 = *(const uint2*)(tsl + (size_t)s0 * SLW);
            uint2 b1 = *(const uint2*)(tsl + (size_t)s1 * SLW);
            A.x += bflo(b0.x) + bflo(b1.x);
            A.y += bfhi(b0.x) + bfhi(b1.x);
            A.z += bflo(b0.y) + bflo(b1.y);
            A.w += bfhi(b0.y) + bfhi(b1.y);
        }
        if (j < end) {
            uint2 b0 = *(const uint2*)(tsl + (size_t)src[j] * SLW);
            A.x += bflo(b0.x); A.y += bfhi(b0.x);
            A.z += bflo(b0.y); A.w += bfhi(b0.y);
        }
        ushort4 o;
        o.x = f2bf(A.x * dv); o.y = f2bf(A.y * dv);
        o.z = f2bf(A.z * dv); o.w = f2bf(A.w * dv);
        *(ushort4*)(hpre + (size_t)v * HH + s * SLW + li * 4) = o;
        float fx = bf1(o.x), fy = bf1(o.y), fz = bf1(o.z), fw = bf1(o.w);
        ssum.x = fx; ssum.y = fy; ssum.z = fz; ssum.w = fw;
        ssq.x = fx * fx; ssq.y = fy * fy; ssq.z = fz * fz; ssq.w = fw * fw;
    }

    // reduce over the wave's 8 subgroups (lanes differing in bits 3..5)
#pragma unroll
    for (int d = 8; d < 64; d <<= 1) {
        ssum.x += __shfl_xor(ssum.x, d, 64);
        ssum.y += __shfl_xor(ssum.y, d, 64);
        ssum.z += __shfl_xor(ssum.z, d, 64);
        ssum.w += __shfl_xor(ssum.w, d, 64);
        ssq.x += __shfl_xor(ssq.x, d, 64);
        ssq.y += __shfl_xor(ssq.y, d, 64);
        ssq.z += __shfl_xor(ssq.z, d, 64);
        ssq.w += __shfl_xor(ssq.w, d, 64);
    }
    if (lane < 8) {
        *(float4*)&lsum[w][lane * 4] = ssum;
        *(float4*)&lsq[w][lane * 4] = ssq;
    }
    __syncthreads();
    int t = threadIdx.x;
    if (t < SLW) {
        float a = 0.f;
#pragma unroll
        for (int ww = 0; ww < 8; ++ww) a += lsum[ww][t];
        atomicAdd(&bns[(nb & 7) * HH + s * SLW + t], a);
    } else if (t < 2 * SLW) {
        int c = t - SLW;
        float a = 0.f;
#pragma unroll
        for (int ww = 0; ww < 8; ++ww) a += lsq[ww][c];
        atomicAdd(&bnq[(nb & 7) * HH + s * SLW + c], a);
    }
}

// ---- normalize + ReLU + weighted residual; bins folded once per block into LDS scale/shift -
__global__ __launch_bounds__(256) void k_bnnorm(const u16* __restrict__ hpre,
                         u16* __restrict__ accb, u16* __restrict__ hb,
                         const float* __restrict__ bins,   // [16][HH]: 8 sum + 8 sq
                         const float* __restrict__ gamma, const float* __restrict__ beta,
                         const float* __restrict__ wArr, int layer) {
    __shared__ float sscale[HH], sshift[HH];
    const float invN = 1.0f / (float)NN;
    {
        int tcol = threadIdx.x;
        float m = 0.f, qq = 0.f;
#pragma unroll
        for (int b = 0; b < 8; ++b) {
            m += bins[b * HH + tcol];
            qq += bins[(8 + b) * HH + tcol];
        }
        m *= invN;
        float var = qq * invN - m * m;
        float sc = rsqrtf(var + EPSB) * gamma[tcol];
        sscale[tcol] = sc;
        sshift[tcol] = beta[tcol] - m * sc;
    }
    __syncthreads();
    int idx = blockIdx.x * blockDim.x + threadIdx.x;
    if (idx >= NN * (HH / 4)) return;
    int c = (idx & 63) << 2;
    float w = wArr[layer];
    ushort4 hv = ((const ushort4*)hpre)[idx];
    ushort4 av = ((const ushort4*)accb)[idx];
    u16* hp = &hv.x;
    u16* ap = &av.x;
    ushort4 oh, oa;
    u16* ohp = &oh.x;
    u16* oap = &oa.x;
#pragma unroll
    for (int k = 0; k < 4; ++k) {
        float v = fmaf(bf1(hp[k]), sscale[c + k], sshift[c + k]);
        v = fmaxf(v, 0.f);
        oap[k] = f2bf(fmaf(w, v, bf1(ap[k])));
        ohp[k] = f2bf(v);
    }
    ((ushort4*)accb)[idx] = oa;
    *(ushort4*)(hb + ((size_t)idx << 2)) = oh;
}

// ---------------- softmax of the 8 layer weights ----------------
__global__ void k_softmaxw(const float* __restrict__ lw, float* __restrict__ wArr) {
    if (threadIdx.x == 0 && blockIdx.x == 0) {
        float m = -3.0e38f;
        for (int i = 0; i < LL; ++i) m = fmaxf(m, lw[i]);
        float e[LL]; float sum = 0.f;
        for (int i = 0; i < LL; ++i) { e[i] = expf(lw[i] - m); sum += e[i]; }
        for (int i = 0; i < LL; ++i) wArr[i] = e[i] / sum;
    }
}

// ---------------- log_softmax rows ----------------
__global__ __launch_bounds__(256) void k_logsoftmax(const float* __restrict__ z,
                                                    float* __restrict__ out) {
    int gt = blockIdx.x * blockDim.x + threadIdx.x;
    int v = gt >> 6;
    int lane = threadIdx.x & 63;
    if (v >= NN) return;
    const float* row = z + (size_t)v * CC;
    float v0 = row[lane];
    float v1 = (lane + 64 < CC) ? row[lane + 64] : -3.0e38f;
    float m = fmaxf(v0, v1);
#pragma unroll
    for (int d = 1; d < 64; d <<= 1) m = fmaxf(m, __shfl_xor(m, d, 64));
    float e = expf(v0 - m) + ((lane + 64 < CC) ? expf(v1 - m) : 0.f);
#pragma unroll
    for (int d = 1; d < 64; d <<= 1) e += __shfl_xor(e, d, 64);
    float lse = m + logf(e);
    out[(size_t)v * CC + lane] = v0 - lse;
    if (lane + 64 < CC) out[(size_t)v * CC + lane + 64] = v1 - lse;
}

extern "C" void kernel_launch(void* const* d_in, const int* in_sizes, int n_in,
                              void* d_out, int out_size, void* d_ws, size_t ws_size,
                              hipStream_t stream) {
    const float* x     = (const float*)d_in[0];
    const int*   e1    = (const int*)d_in[1];
    const int*   e2    = (const int*)d_in[2];
    const float* inW   = (const float*)d_in[3];
    const float* inb   = (const float*)d_in[4];
    const float* convW = (const float*)d_in[5];
    const float* convB = (const float*)d_in[6];
    const float* gamma = (const float*)d_in[7];
    const float* beta  = (const float*)d_in[8];
    const float* outW  = (const float*)d_in[9];
    const float* outb  = (const float*)d_in[10];
    const float* lw    = (const float*)d_in[11];

    char* ws = (char*)d_ws;
    size_t off = 0;
    auto alloc = [&](size_t bytes) -> void* {
        void* p = ws + off;
        off = (off + bytes + 255) & ~(size_t)255;
        return p;
    };
    u16*   hb    = (u16*)alloc((size_t)NN * HH * 2);     // bf16 h (GEMM A)
    u16*   tb    = (u16*)alloc((size_t)NN * HH * 2);     // bf16 t' SLICED [8][NN][32]; alias xb
    u16*   hpre  = (u16*)alloc((size_t)NN * HH * 2);     // spmm out; alias logits(f32)
    u16*   accb  = (u16*)alloc((size_t)NN * HH * 2);     // bf16 residual accumulator
    u16*   convWt= (u16*)alloc((size_t)LL * HH * HH * 2);
    u16*   inWt  = (u16*)alloc((size_t)HH * FIN * 2);
    u16*   outWt = (u16*)alloc((size_t)128 * HH * 2);
    float* obb   = (float*)alloc(128 * 4);
    float* dinv1 = (float*)alloc((size_t)NN * 4);
    float* dinv2 = (float*)alloc((size_t)NN * 4);
    u16*   src1p = (u16*)alloc((size_t)NN * 64 * 2);     // padded CSR, 64 u16 slots/node
    u16*   src2p = (u16*)alloc((size_t)NN * 64 * 2);
    int*   curz  = (int*)alloc((size_t)2 * NN * 4);      // cur1,cur2 (degree counters)
    float* bnsq  = (float*)alloc((size_t)LL * 16 * HH * 4);  // per layer: 8 sum + 8 sq bins
    float* wArr  = (float*)alloc(64);
    u32*   bucket= (u32*)alloc((size_t)16 * BCAP * 4);   // edge partition buckets (7 MB)
    int*   bcnt  = (int*)alloc(16 * 4);
    u16*   perm1 = (u16*)alloc((size_t)NN * 2);          // degree-sorted node order, graph1
    u16*   perm2 = (u16*)alloc((size_t)NN * 2);          // graph2
    int*   dhist = (int*)alloc(128 * 4);                 // 64 degree bins x 2 graphs
    int*   doff  = (int*)alloc(128 * 4);
    u16*   xb    = tb;            // x_bf16 dead once layer-0 conv GEMM writes tb
    float* logits = (float*)hpre; // fp32 logits: hpre free after last bnnorm

    int* cur1 = curz;

    hipMemsetAsync(curz, 0, (size_t)2 * NN * 4, stream);
    hipMemsetAsync(bnsq, 0, (size_t)LL * 16 * HH * 4, stream);
    hipMemsetAsync(accb, 0, (size_t)NN * HH * 2, stream);
    hipMemsetAsync(bcnt, 0, 16 * 4, stream);
    hipMemsetAsync(dhist, 0, 128 * 4, stream);

    // padded CSR build: two-pass bucket partition, then degree counting-sort (perm1/perm2)
    k_part<<<(2 * EE + 2047) / 2048, 256, 0, stream>>>(e1, e2, bcnt, bucket);
    k_fillB<<<16 * 64, 256, 0, stream>>>(bucket, bcnt, curz, src1p, src2p);
    k_dinv2<<<(2 * NN + 255) / 256, 256, 0, stream>>>(curz, dinv1, dinv2, dhist, NN);
    k_dscan<<<1, 64, 0, stream>>>(dhist, doff);
    k_dplace<<<(2 * NN + 255) / 256, 256, 0, stream>>>(curz, doff, perm1, perm2, NN);

    k_softmaxw<<<1, 64, 0, stream>>>(lw, wArr);

    // weight prep
    {
        dim3 g(HH / 32, HH / 32, LL);
        dim3 b(32, 8);
        k_wt<<<g, b, 0, stream>>>(convW, convWt, HH, HH);
        dim3 g2(HH / 32, FIN / 32, 1);
        k_wt<<<g2, b, 0, stream>>>(inW, inWt, FIN, HH);
        k_outwt<<<128, 256, 0, stream>>>(outW, outb, outWt, obb);
    }
    k_xcast<<<(NN * FIN / 4 + 255) / 256, 256, 0, stream>>>(x, xb, NN * FIN / 4);

    const int MT = (NN + 127) / 128;               // 391
    const int GSW = ((MT + 7) / 8) * 16;           // swizzled grid: 784
    // input FC: hb = bf16( x @ inW + inb )   (standard layout: next GEMM's A)
    k_gemm_bf16<false, true, false><<<GSW, 256, 0, stream>>>(xb, inWt, inb, nullptr, hb,
                                                             NN, HH, FIN);

    const int NBL = (NN + 63) / 64;                // 782 node-blocks (64 nodes each)
    const int SPB = NBL * NSL;                     // 782 x 8 slices = 6256 (% 8 == 0)
    const int ELB = (NN * (HH / 4) + 255) / 256;
    for (int i = 0; i < LL; ++i) {
        const int* dg = (i < LL / 2) ? cur1 : (curz + NN);
        const u16* sr = (i < LL / 2) ? src1p : src2p;
        const float* dv = (i < LL / 2) ? dinv1 : dinv2;
        const u16* pm = (i < LL / 2) ? perm1 : perm2;
        float* bins = bnsq + (size_t)i * 16 * HH;
        // tb = bf16( dinv[r] * (hb @ convW_i + convB_i) )  in SLICED layout
        k_gemm_bf16<false, true, true><<<GSW, 256, 0, stream>>>(hb,
                                                          convWt + (size_t)i * HH * HH,
                                                          convB + (size_t)i * HH, dv, tb,
                                                          NN, HH, HH);
        k_spmm_sl8<<<SPB, 512, 0, stream>>>(tb, dg, sr, dv, pm, hpre, bins, bins + 8 * HH);
        k_bnnorm<<<ELB, 256, 0, stream>>>(hpre, accb, hb, bins,
                                          gamma + (size_t)i * HH, beta + (size_t)i * HH,
                                          wArr, i);
    }

    // out FC: logits = accb @ outWt^T + obb   (fp32 store into hpre, Nc=112, single n-tile)
    k_gemm_bf16<true, false, false><<<MT, 256, 0, stream>>>(accb, outWt, obb, nullptr, logits,
                                                            NN, CC, HH);
    k_logsoftmax<<<NN / 4, 256, 0, stream>>>(logits, (float*)d_out);
}

// Round 10
// 1238.687 us; speedup vs baseline: 1.1980x; 1.1980x over previous
//
#include <hip/hip_runtime.h>
#include <math.h>

#define NN 50000
#define HH 256
#define FIN 128
#define CC 112
#define LL 8
#define EE 800000
#define EPSB 1e-5f
#define NGRP 8
#define NPG (NN / NGRP)     // 6250 nodes per XCD-group
#define SLW 32              // spmm column-slice width (u16 -> 64 B/row = 1 line)
#define NSL (HH / SLW)      // 8 slices, one per XCD
#define BCAP 110000         // bucket capacity (Binomial(800k,1/8): mean 100k, +33 sigma)

typedef unsigned short u16;
typedef unsigned int u32;
typedef __attribute__((ext_vector_type(8))) short bf16x8;
typedef __attribute__((ext_vector_type(4))) float f32x4;

__device__ __forceinline__ u16 f2bf(float f) {
    u32 u = __float_as_uint(f);
    u32 r = (u + 0x7FFFu + ((u >> 16) & 1u)) >> 16;   // RNE
    return (u16)r;
}
__device__ __forceinline__ float bflo(u32 u) { return __uint_as_float(u << 16); }
__device__ __forceinline__ float bfhi(u32 u) { return __uint_as_float(u & 0xFFFF0000u); }
__device__ __forceinline__ float bf1(u16 u) { return __uint_as_float(((u32)u) << 16); }

// v_dot2_f32_bf16: D = S0.lo*S1.lo + S0.hi*S1.hi + S2. Selector 0x00003F80 (bf16 1.0 in lo
// half) extracts+accumulates the LOW bf16 col in ONE VALU op (replaces shl+add); 0x3F800000
// the HIGH col (replaces and+add). Halves the spmm inner-loop VALU.
__device__ __forceinline__ float dot2lo(u32 p, float acc, u32 sel) {
    float r;
    asm("v_dot2_f32_bf16 %0, %1, %2, %3" : "=v"(r) : "v"(p), "v"(sel), "v"(acc));
    return r;
}

__device__ __forceinline__ void gload16(const u16* g, u16* l) {
    __builtin_amdgcn_global_load_lds(
        (const __attribute__((address_space(1))) void*)g,
        (__attribute__((address_space(3))) void*)l, 16, 0, 0);
}

// ---------------- CSR build pass A: partition edges into 16 buckets --------------------------
__global__ __launch_bounds__(256) void k_part(const int* __restrict__ ed1,
                                              const int* __restrict__ ed2,
                                              int* __restrict__ bcnt,
                                              u32* __restrict__ bucket) {
    __shared__ int hist[16], base[16], cnt2[16];
    const int t = threadIdx.x;
    if (t < 16) { hist[t] = 0; cnt2[t] = 0; }
    __syncthreads();
    const int e0 = blockIdx.x * 2048;
    int myb[8]; u32 myp[8];
#pragma unroll
    for (int k = 0; k < 8; ++k) {
        int e = e0 + k * 256 + t;
        myb[k] = -1;
        if (e < 2 * EE) {
            const int* ed = (e < EE) ? ed1 : ed2;
            int ee = (e < EE) ? e : e - EE;
            int c = ed[ee + EE];
            int r = ed[ee];
            int b = ((e >= EE) ? 8 : 0) | (c / NPG);
            myb[k] = b;
            myp[k] = ((u32)c << 16) | (u32)r;
            atomicAdd(&hist[b], 1);
        }
    }
    __syncthreads();
    if (t < 16) base[t] = atomicAdd(&bcnt[t], hist[t]);
    __syncthreads();
#pragma unroll
    for (int k = 0; k < 8; ++k) {
        if (myb[k] >= 0) {
            int off = atomicAdd(&cnt2[myb[k]], 1);
            bucket[(size_t)myb[k] * BCAP + base[myb[k]] + off] = myp[k];
        }
    }
}

// ---------------- CSR build pass B: per-XCD scatter from own bucket --------------------------
__global__ __launch_bounds__(256) void k_fillB(const u32* __restrict__ bucket,
                                               const int* __restrict__ bcnt,
                                               int* __restrict__ cur,
                                               u16* __restrict__ src1p,
                                               u16* __restrict__ src2p) {
    const int b = blockIdx.x & 15;
    const int n = bcnt[b];
    u16* sp = (b < 8) ? src1p : src2p;
    int* cu = (b < 8) ? cur : cur + NN;
    const u32* bk = bucket + (size_t)b * BCAP;
    const int stride = (gridDim.x >> 4) * 256;
    for (int i = (blockIdx.x >> 4) * 256 + threadIdx.x; i < n; i += stride) {
        u32 p = bk[i];
        int c = p >> 16;
        int r = p & 0xFFFFu;
        int pos = atomicAdd(&cu[c], 1);
        sp[(c << 6) + pos] = (u16)r;
    }
}

__global__ void k_dinv2(const int* __restrict__ deg, float* __restrict__ dinv1,
                        float* __restrict__ dinv2, int n) {
    int v = blockIdx.x * blockDim.x + threadIdx.x;
    if (v >= 2 * n) return;
    float* d = (v < n) ? dinv1 : dinv2;
    int vv = (v < n) ? v : v - n;
    d[vv] = rsqrtf((float)(deg[v] + 1));  // +1 self-loop
}

// ---------------- weight transpose + bf16 cast: W[K][N] f32 -> Wt[N][K] bf16 ----------------
__global__ void k_wt(const float* __restrict__ W, u16* __restrict__ Wt, int K, int N) {
    __shared__ u16 sm[32][33];
    const float* Wl = W + (size_t)blockIdx.z * K * N;
    u16* Wtl = Wt + (size_t)blockIdx.z * K * N;
    int k0 = blockIdx.y * 32, n0 = blockIdx.x * 32;
    int tx = threadIdx.x, ty = threadIdx.y;  // 32 x 8
#pragma unroll
    for (int r = 0; r < 32; r += 8)
        sm[ty + r][tx] = f2bf(Wl[(size_t)(k0 + ty + r) * N + n0 + tx]);
    __syncthreads();
#pragma unroll
    for (int r = 0; r < 32; r += 8)
        Wtl[(size_t)(n0 + ty + r) * K + k0 + tx] = sm[tx][ty + r];
}

// outW [H=256][C=112] f32 -> outWt [128][256] bf16 (rows >= C zero); pad bias to 128
__global__ void k_outwt(const float* __restrict__ outW, const float* __restrict__ outb,
                        u16* __restrict__ outWt, float* __restrict__ obb) {
    int idx = blockIdx.x * 256 + threadIdx.x;     // 128*256
    if (idx >= 128 * 256) return;
    int n = idx >> 8, k = idx & 255;
    float v = (n < CC) ? outW[(size_t)k * CC + n] : 0.f;
    outWt[(size_t)n * HH + k] = f2bf(v);
    if (idx < 128) obb[idx] = (idx < CC) ? outb[idx] : 0.f;
}

// ---------------- fp32 -> bf16 cast ----------------
__global__ void k_xcast(const float* __restrict__ x, u16* __restrict__ xb, int n4) {
    int i = blockIdx.x * blockDim.x + threadIdx.x;
    if (i >= n4) return;
    float4 v = ((const float4*)x)[i];
    ushort4 o;
    o.x = f2bf(v.x); o.y = f2bf(v.y); o.z = f2bf(v.z); o.w = f2bf(v.w);
    *(ushort4*)(xb + ((size_t)i << 2)) = o;
}

// ---- bf16 MFMA GEMM: C = A @ Bt^T + bias, per-row scale; XCD-aware m/n swizzle when SWIZ ---
// SLICED: store u16 C in column-sliced layout [Nc/32][M][32] for the L2-pinned spmm gather.
template <bool F32OUT, bool SWIZ, bool SLICED>
__global__ __launch_bounds__(256) void k_gemm_bf16(const u16* __restrict__ A,
                                                   const u16* __restrict__ Bt,
                                                   const float* __restrict__ bias,
                                                   const float* __restrict__ rowscale,
                                                   void* __restrict__ Cout,
                                                   int M, int Nc, int K) {
    int m0, n0;
    if (SWIZ) {
        int id = blockIdx.x;
        int g = id >> 4, r = id & 15;
        int m = g * 8 + (r & 7);
        if (m * 128 >= M) return;
        m0 = m * 128;
        n0 = (r >> 3) * 128;
    } else {
        m0 = blockIdx.x * 128;
        n0 = 0;
    }
    __shared__ u16 As[128 * 32];
    __shared__ u16 Bs[128 * 32];
    const int tid = threadIdx.x;
    const int w = tid >> 6, lane = tid & 63;
    const int wr = (w >> 1) * 64, wc = (w & 1) * 64;
    const int lm = lane & 15, lq = lane >> 4;

    f32x4 acc[4][4];
#pragma unroll
    for (int i = 0; i < 4; ++i)
#pragma unroll
        for (int j = 0; j < 4; ++j) acc[i][j] = (f32x4){0.f, 0.f, 0.f, 0.f};

    const int srow = w * 16 + (lane >> 2);
    const int scol = (lane & 3) * 8;

    for (int k0 = 0; k0 < K; k0 += 32) {
        int gm = m0 + srow;        if (gm >= M) gm = M - 1;
        gload16(A + (size_t)gm * K + k0 + scol, As + (size_t)(w * 64) * 8);
        int gm2 = m0 + 64 + srow;  if (gm2 >= M) gm2 = M - 1;
        gload16(A + (size_t)gm2 * K + k0 + scol, As + (size_t)(256 + w * 64) * 8);
        gload16(Bt + (size_t)(n0 + srow) * K + k0 + scol, Bs + (size_t)(w * 64) * 8);
        gload16(Bt + (size_t)(n0 + 64 + srow) * K + k0 + scol, Bs + (size_t)(256 + w * 64) * 8);
        __syncthreads();

        bf16x8 af[4], bfr[4];
#pragma unroll
        for (int i = 0; i < 4; ++i)
            af[i] = *(const bf16x8*)(As + (wr + i * 16 + lm) * 32 + lq * 8);
#pragma unroll
        for (int j = 0; j < 4; ++j)
            bfr[j] = *(const bf16x8*)(Bs + (wc + j * 16 + lm) * 32 + lq * 8);
#pragma unroll
        for (int i = 0; i < 4; ++i)
#pragma unroll
            for (int j = 0; j < 4; ++j)
                acc[i][j] = __builtin_amdgcn_mfma_f32_16x16x32_bf16(af[i], bfr[j], acc[i][j], 0, 0, 0);
        __syncthreads();
    }

    // epilogue: C/D layout col=lane&15, row=(lane>>4)*4+reg  [m89-verified]
#pragma unroll
    for (int j = 0; j < 4; ++j) {
        int gc = n0 + wc + j * 16 + lm;
        float bj = (gc < Nc) ? bias[gc] : 0.f;
#pragma unroll
        for (int i = 0; i < 4; ++i) {
#pragma unroll
            for (int r = 0; r < 4; ++r) {
                int gr = m0 + wr + i * 16 + lq * 4 + r;
                if (gr < M && gc < Nc) {
                    float rs = rowscale ? rowscale[gr] : 1.0f;
                    float val = (acc[i][j][r] + bj) * rs;
                    if (F32OUT)
                        ((float*)Cout)[(size_t)gr * Nc + gc] = val;
                    else if (SLICED)
                        ((u16*)Cout)[((size_t)(gc >> 5) * M + gr) * SLW + (gc & 31)] = f2bf(val);
                    else
                        ((u16*)Cout)[(size_t)gr * Nc + gc] = f2bf(val);
                }
            }
        }
    }
}

// -- column-sliced gather SpMM, 8-lane row-subgroups, dot2 accumulate ------------------------
// slice = blockIdx & 7 -> pinned to one XCD; 3.2 MB L2-resident slice; 512 B/instr.
// Round-8 diagnosis (ERRATA-15 unit fix): VALU floor ~11 us/layer, measured VALU-busy 31 us
// (3x: unpack+add+addressing), stall ~37 us. v_dot2_f32_bf16 fuses unpack+add (8 VALU ->
// 4 VALU per gathered uint2) -> attack the 31 us busy component.
__global__ __launch_bounds__(512) void k_spmm_sl8(const u16* __restrict__ ts,
                                                  const int* __restrict__ deg,
                                                  const u16* __restrict__ srcp,
                                                  const float* __restrict__ dinv,
                                                  u16* __restrict__ hpre,
                                                  float* __restrict__ bns,   // [8][HH]
                                                  float* __restrict__ bnq) { // [8][HH]
    __shared__ float lsum[8][SLW];
    __shared__ float lsq[8][SLW];
    const int s = blockIdx.x & 7;
    const int nb = blockIdx.x >> 3;
    const int w = threadIdx.x >> 6;
    const int lane = threadIdx.x & 63;
    const int sub = lane >> 3;          // node subgroup 0..7
    const int li = lane & 7;            // lane covers cols 4li..4li+3 of the slice (uint2)
    const u16* tsl = ts + (size_t)s * NN * SLW + li * 4;
    const u32 SLO = 0x00003F80u;        // bf16 1.0 in lo half -> select low col
    const u32 SHI = 0x3F800000u;        // bf16 1.0 in hi half -> select high col

    const int v = nb * 64 + w * 8 + sub;
    float4 ssum = make_float4(0.f, 0.f, 0.f, 0.f);
    float4 ssq  = make_float4(0.f, 0.f, 0.f, 0.f);

    if (v < NN) {
        const u16* src = srcp + ((size_t)v << 6);
        const float dv = dinv[v];
        uint2 a = *(const uint2*)(tsl + (size_t)v * SLW);
        float4 A;
        A.x = bflo(a.x); A.y = bfhi(a.x); A.z = bflo(a.y); A.w = bfhi(a.y);
        int end = deg[v];
        int j = 0;
        for (; j + 8 <= end; j += 8) {
            uint4 sp = *(const uint4*)(src + j);   // 8 packed u16 indices (subgroup-bcast)
            uint2 b0 = *(const uint2*)(tsl + (size_t)(sp.x & 0xFFFFu) * SLW);
            uint2 b1 = *(const uint2*)(tsl + (size_t)(sp.x >> 16) * SLW);
            uint2 b2 = *(const uint2*)(tsl + (size_t)(sp.y & 0xFFFFu) * SLW);
            uint2 b3 = *(const uint2*)(tsl + (size_t)(sp.y >> 16) * SLW);
            uint2 b4 = *(const uint2*)(tsl + (size_t)(sp.z & 0xFFFFu) * SLW);
            uint2 b5 = *(const uint2*)(tsl + (size_t)(sp.z >> 16) * SLW);
            uint2 b6 = *(const uint2*)(tsl + (size_t)(sp.w & 0xFFFFu) * SLW);
            uint2 b7 = *(const uint2*)(tsl + (size_t)(sp.w >> 16) * SLW);
            A.x = dot2lo(b0.x, A.x, SLO); A.y = dot2lo(b0.x, A.y, SHI);
            A.z = dot2lo(b0.y, A.z, SLO); A.w = dot2lo(b0.y, A.w, SHI);
            A.x = dot2lo(b1.x, A.x, SLO); A.y = dot2lo(b1.x, A.y, SHI);
            A.z = dot2lo(b1.y, A.z, SLO); A.w = dot2lo(b1.y, A.w, SHI);
            A.x = dot2lo(b2.x, A.x, SLO); A.y = dot2lo(b2.x, A.y, SHI);
            A.z = dot2lo(b2.y, A.z, SLO); A.w = dot2lo(b2.y, A.w, SHI);
            A.x = dot2lo(b3.x, A.x, SLO); A.y = dot2lo(b3.x, A.y, SHI);
            A.z = dot2lo(b3.y, A.z, SLO); A.w = dot2lo(b3.y, A.w, SHI);
            A.x = dot2lo(b4.x, A.x, SLO); A.y = dot2lo(b4.x, A.y, SHI);
            A.z = dot2lo(b4.y, A.z, SLO); A.w = dot2lo(b4.y, A.w, SHI);
            A.x = dot2lo(b5.x, A.x, SLO); A.y = dot2lo(b5.x, A.y, SHI);
            A.z = dot2lo(b5.y, A.z, SLO); A.w = dot2lo(b5.y, A.w, SHI);
            A.x = dot2lo(b6.x, A.x, SLO); A.y = dot2lo(b6.x, A.y, SHI);
            A.z = dot2lo(b6.y, A.z, SLO); A.w = dot2lo(b6.y, A.w, SHI);
            A.x = dot2lo(b7.x, A.x, SLO); A.y = dot2lo(b7.x, A.y, SHI);
            A.z = dot2lo(b7.y, A.z, SLO); A.w = dot2lo(b7.y, A.w, SHI);
        }
        for (; j + 2 <= end; j += 2) {
            int s0 = src[j], s1 = src[j + 1];
            uint2 b0 = *(const uint2*)(tsl + (size_t)s0 * SLW);
            uint2 b1 = *(const uint2*)(tsl + (size_t)s1 * SLW);
            A.x = dot2lo(b0.x, A.x, SLO); A.y = dot2lo(b0.x, A.y, SHI);
            A.z = dot2lo(b0.y, A.z, SLO); A.w = dot2lo(b0.y, A.w, SHI);
            A.x = dot2lo(b1.x, A.x, SLO); A.y = dot2lo(b1.x, A.y, SHI);
            A.z = dot2lo(b1.y, A.z, SLO); A.w = dot2lo(b1.y, A.w, SHI);
        }
        if (j < end) {
            uint2 b0 = *(const uint2*)(tsl + (size_t)src[j] * SLW);
            A.x = dot2lo(b0.x, A.x, SLO); A.y = dot2lo(b0.x, A.y, SHI);
            A.z = dot2lo(b0.y, A.z, SLO); A.w = dot2lo(b0.y, A.w, SHI);
        }
        ushort4 o;
        o.x = f2bf(A.x * dv); o.y = f2bf(A.y * dv);
        o.z = f2bf(A.z * dv); o.w = f2bf(A.w * dv);
        *(ushort4*)(hpre + (size_t)v * HH + s * SLW + li * 4) = o;
        float fx = bf1(o.x), fy = bf1(o.y), fz = bf1(o.z), fw = bf1(o.w);
        ssum.x = fx; ssum.y = fy; ssum.z = fz; ssum.w = fw;
        ssq.x = fx * fx; ssq.y = fy * fy; ssq.z = fz * fz; ssq.w = fw * fw;
    }

    // reduce over the wave's 8 subgroups (lanes differing in bits 3..5)
#pragma unroll
    for (int d = 8; d < 64; d <<= 1) {
        ssum.x += __shfl_xor(ssum.x, d, 64);
        ssum.y += __shfl_xor(ssum.y, d, 64);
        ssum.z += __shfl_xor(ssum.z, d, 64);
        ssum.w += __shfl_xor(ssum.w, d, 64);
        ssq.x += __shfl_xor(ssq.x, d, 64);
        ssq.y += __shfl_xor(ssq.y, d, 64);
        ssq.z += __shfl_xor(ssq.z, d, 64);
        ssq.w += __shfl_xor(ssq.w, d, 64);
    }
    if (lane < 8) {
        *(float4*)&lsum[w][lane * 4] = ssum;
        *(float4*)&lsq[w][lane * 4] = ssq;
    }
    __syncthreads();
    int t = threadIdx.x;
    if (t < SLW) {
        float a = 0.f;
#pragma unroll
        for (int ww = 0; ww < 8; ++ww) a += lsum[ww][t];
        atomicAdd(&bns[(nb & 7) * HH + s * SLW + t], a);
    } else if (t < 2 * SLW) {
        int c = t - SLW;
        float a = 0.f;
#pragma unroll
        for (int ww = 0; ww < 8; ++ww) a += lsq[ww][c];
        atomicAdd(&bnq[(nb & 7) * HH + s * SLW + c], a);
    }
}

// ---- normalize + ReLU + weighted residual; bins folded once per block into LDS scale/shift -
__global__ __launch_bounds__(256) void k_bnnorm(const u16* __restrict__ hpre,
                         u16* __restrict__ accb, u16* __restrict__ hb,
                         const float* __restrict__ bins,   // [16][HH]: 8 sum + 8 sq
                         const float* __restrict__ gamma, const float* __restrict__ beta,
                         const float* __restrict__ wArr, int layer) {
    __shared__ float sscale[HH], sshift[HH];
    const float invN = 1.0f / (float)NN;
    {
        int tcol = threadIdx.x;
        float m = 0.f, qq = 0.f;
#pragma unroll
        for (int b = 0; b < 8; ++b) {
            m += bins[b * HH + tcol];
            qq += bins[(8 + b) * HH + tcol];
        }
        m *= invN;
        float var = qq * invN - m * m;
        float sc = rsqrtf(var + EPSB) * gamma[tcol];
        sscale[tcol] = sc;
        sshift[tcol] = beta[tcol] - m * sc;
    }
    __syncthreads();
    int idx = blockIdx.x * blockDim.x + threadIdx.x;
    if (idx >= NN * (HH / 4)) return;
    int c = (idx & 63) << 2;
    float w = wArr[layer];
    ushort4 hv = ((const ushort4*)hpre)[idx];
    ushort4 av = ((const ushort4*)accb)[idx];
    u16* hp = &hv.x;
    u16* ap = &av.x;
    ushort4 oh, oa;
    u16* ohp = &oh.x;
    u16* oap = &oa.x;
#pragma unroll
    for (int k = 0; k < 4; ++k) {
        float v = fmaf(bf1(hp[k]), sscale[c + k], sshift[c + k]);
        v = fmaxf(v, 0.f);
        oap[k] = f2bf(fmaf(w, v, bf1(ap[k])));
        ohp[k] = f2bf(v);
    }
    ((ushort4*)accb)[idx] = oa;
    *(ushort4*)(hb + ((size_t)idx << 2)) = oh;
}

// ---------------- softmax of the 8 layer weights ----------------
__global__ void k_softmaxw(const float* __restrict__ lw, float* __restrict__ wArr) {
    if (threadIdx.x == 0 && blockIdx.x == 0) {
        float m = -3.0e38f;
        for (int i = 0; i < LL; ++i) m = fmaxf(m, lw[i]);
        float e[LL]; float sum = 0.f;
        for (int i = 0; i < LL; ++i) { e[i] = expf(lw[i] - m); sum += e[i]; }
        for (int i = 0; i < LL; ++i) wArr[i] = e[i] / sum;
    }
}

// ---------------- log_softmax rows ----------------
__global__ __launch_bounds__(256) void k_logsoftmax(const float* __restrict__ z,
                                                    float* __restrict__ out) {
    int gt = blockIdx.x * blockDim.x + threadIdx.x;
    int v = gt >> 6;
    int lane = threadIdx.x & 63;
    if (v >= NN) return;
    const float* row = z + (size_t)v * CC;
    float v0 = row[lane];
    float v1 = (lane + 64 < CC) ? row[lane + 64] : -3.0e38f;
    float m = fmaxf(v0, v1);
#pragma unroll
    for (int d = 1; d < 64; d <<= 1) m = fmaxf(m, __shfl_xor(m, d, 64));
    float e = expf(v0 - m) + ((lane + 64 < CC) ? expf(v1 - m) : 0.f);
#pragma unroll
    for (int d = 1; d < 64; d <<= 1) e += __shfl_xor(e, d, 64);
    float lse = m + logf(e);
    out[(size_t)v * CC + lane] = v0 - lse;
    if (lane + 64 < CC) out[(size_t)v * CC + lane + 64] = v1 - lse;
}

extern "C" void kernel_launch(void* const* d_in, const int* in_sizes, int n_in,
                              void* d_out, int out_size, void* d_ws, size_t ws_size,
                              hipStream_t stream) {
    const float* x     = (const float*)d_in[0];
    const int*   e1    = (const int*)d_in[1];
    const int*   e2    = (const int*)d_in[2];
    const float* inW   = (const float*)d_in[3];
    const float* inb   = (const float*)d_in[4];
    const float* convW = (const float*)d_in[5];
    const float* convB = (const float*)d_in[6];
    const float* gamma = (const float*)d_in[7];
    const float* beta  = (const float*)d_in[8];
    const float* outW  = (const float*)d_in[9];
    const float* outb  = (const float*)d_in[10];
    const float* lw    = (const float*)d_in[11];

    char* ws = (char*)d_ws;
    size_t off = 0;
    auto alloc = [&](size_t bytes) -> void* {
        void* p = ws + off;
        off = (off + bytes + 255) & ~(size_t)255;
        return p;
    };
    u16*   hb    = (u16*)alloc((size_t)NN * HH * 2);     // bf16 h (GEMM A)
    u16*   tb    = (u16*)alloc((size_t)NN * HH * 2);     // bf16 t' SLICED [8][NN][32]; alias xb
    u16*   hpre  = (u16*)alloc((size_t)NN * HH * 2);     // spmm out; alias logits(f32)
    u16*   accb  = (u16*)alloc((size_t)NN * HH * 2);     // bf16 residual accumulator
    u16*   convWt= (u16*)alloc((size_t)LL * HH * HH * 2);
    u16*   inWt  = (u16*)alloc((size_t)HH * FIN * 2);
    u16*   outWt = (u16*)alloc((size_t)128 * HH * 2);
    float* obb   = (float*)alloc(128 * 4);
    float* dinv1 = (float*)alloc((size_t)NN * 4);
    float* dinv2 = (float*)alloc((size_t)NN * 4);
    u16*   src1p = (u16*)alloc((size_t)NN * 64 * 2);     // padded CSR, 64 u16 slots/node
    u16*   src2p = (u16*)alloc((size_t)NN * 64 * 2);
    int*   curz  = (int*)alloc((size_t)2 * NN * 4);      // cur1,cur2 (degree counters)
    float* bnsq  = (float*)alloc((size_t)LL * 16 * HH * 4);  // per layer: 8 sum + 8 sq bins
    float* wArr  = (float*)alloc(64);
    u32*   bucket= (u32*)alloc((size_t)16 * BCAP * 4);   // edge partition buckets (7 MB)
    int*   bcnt  = (int*)alloc(16 * 4);
    u16*   xb    = tb;            // x_bf16 dead once layer-0 conv GEMM writes tb
    float* logits = (float*)hpre; // fp32 logits: hpre free after last bnnorm

    int* cur1 = curz;

    hipMemsetAsync(curz, 0, (size_t)2 * NN * 4, stream);
    hipMemsetAsync(bnsq, 0, (size_t)LL * 16 * HH * 4, stream);
    hipMemsetAsync(accb, 0, (size_t)NN * HH * 2, stream);
    hipMemsetAsync(bcnt, 0, 16 * 4, stream);

    // padded CSR build: two-pass bucket partition (pass A: 16-way split; pass B: per-XCD fill)
    k_part<<<(2 * EE + 2047) / 2048, 256, 0, stream>>>(e1, e2, bcnt, bucket);
    k_fillB<<<16 * 64, 256, 0, stream>>>(bucket, bcnt, curz, src1p, src2p);
    k_dinv2<<<(2 * NN + 255) / 256, 256, 0, stream>>>(curz, dinv1, dinv2, NN);

    k_softmaxw<<<1, 64, 0, stream>>>(lw, wArr);

    // weight prep
    {
        dim3 g(HH / 32, HH / 32, LL);
        dim3 b(32, 8);
        k_wt<<<g, b, 0, stream>>>(convW, convWt, HH, HH);
        dim3 g2(HH / 32, FIN / 32, 1);
        k_wt<<<g2, b, 0, stream>>>(inW, inWt, FIN, HH);
        k_outwt<<<128, 256, 0, stream>>>(outW, outb, outWt, obb);
    }
    k_xcast<<<(NN * FIN / 4 + 255) / 256, 256, 0, stream>>>(x, xb, NN * FIN / 4);

    const int MT = (NN + 127) / 128;               // 391
    const int GSW = ((MT + 7) / 8) * 16;           // swizzled grid: 784
    // input FC: hb = bf16( x @ inW + inb )   (standard layout: next GEMM's A)
    k_gemm_bf16<false, true, false><<<GSW, 256, 0, stream>>>(xb, inWt, inb, nullptr, hb,
                                                             NN, HH, FIN);

    const int NBL = (NN + 63) / 64;                // 782 node-blocks (64 nodes each)
    const int SPB = NBL * NSL;                     // 782 x 8 slices = 6256 (% 8 == 0)
    const int ELB = (NN * (HH / 4) + 255) / 256;
    for (int i = 0; i < LL; ++i) {
        const int* dg = (i < LL / 2) ? cur1 : (curz + NN);
        const u16* sr = (i < LL / 2) ? src1p : src2p;
        const float* dv = (i < LL / 2) ? dinv1 : dinv2;
        float* bins = bnsq + (size_t)i * 16 * HH;
        // tb = bf16( dinv[r] * (hb @ convW_i + convB_i) )  in SLICED layout
        k_gemm_bf16<false, true, true><<<GSW, 256, 0, stream>>>(hb,
                                                          convWt + (size_t)i * HH * HH,
                                                          convB + (size_t)i * HH, dv, tb,
                                                          NN, HH, HH);
        k_spmm_sl8<<<SPB, 512, 0, stream>>>(tb, dg, sr, dv, hpre, bins, bins + 8 * HH);
        k_bnnorm<<<ELB, 256, 0, stream>>>(hpre, accb, hb, bins,
                                          gamma + (size_t)i * HH, beta + (size_t)i * HH,
                                          wArr, i);
    }

    // out FC: logits = accb @ outWt^T + obb   (fp32 store into hpre, Nc=112, single n-tile)
    k_gemm_bf16<true, false, false><<<MT, 256, 0, stream>>>(accb, outWt, obb, nullptr, logits,
                                                            NN, CC, HH);
    k_logsoftmax<<<NN / 4, 256, 0, stream>>>(logits, (float*)d_out);
}

// Round 11
// 1144.820 us; speedup vs baseline: 1.2962x; 1.0820x over previous
//
#include <hip/hip_runtime.h>
#include <math.h>

#define NN 50000
#define HH 256
#define FIN 128
#define CC 112
#define LL 8
#define EE 800000
#define EPSB 1e-5f
#define NGRP 8
#define NPG (NN / NGRP)     // 6250 nodes per XCD-group
#define SLW 32              // spmm column-slice width (u16 -> 64 B/row = 1 line)
#define NSL (HH / SLW)      // 8 slices, one per XCD

typedef unsigned short u16;
typedef unsigned int u32;
typedef __attribute__((ext_vector_type(8))) short bf16x8;
typedef __attribute__((ext_vector_type(4))) float f32x4;

__device__ __forceinline__ u16 f2bf(float f) {
    u32 u = __float_as_uint(f);
    u32 r = (u + 0x7FFFu + ((u >> 16) & 1u)) >> 16;   // RNE
    return (u16)r;
}
__device__ __forceinline__ float bflo(u32 u) { return __uint_as_float(u << 16); }
__device__ __forceinline__ float bfhi(u32 u) { return __uint_as_float(u & 0xFFFF0000u); }
__device__ __forceinline__ float bf1(u16 u) { return __uint_as_float(((u32)u) << 16); }

__device__ __forceinline__ void gload16(const u16* g, u16* l) {
    __builtin_amdgcn_global_load_lds(
        (const __attribute__((address_space(1))) void*)g,
        (__attribute__((address_space(3))) void*)l, 16, 0, 0);
}

// ---------------- padded CSR build, XCD-partitioned (round-1/5 best config) ----------------
__global__ __launch_bounds__(256) void k_fill2(const int* __restrict__ ed1,
                                               const int* __restrict__ ed2,
                                               int* __restrict__ cur,
                                               u16* __restrict__ src1p,
                                               u16* __restrict__ src2p) {
    const int g = blockIdx.x & 7;
    const int bg = blockIdx.x >> 3;
    const int nthr = (gridDim.x >> 3) * 256;
    const int tid = bg * 256 + threadIdx.x;
    const int lo = g * NPG;

    for (int e = tid; e < EE; e += nthr) {
        int c = ed1[e + EE];
        if ((u32)(c - lo) < (u32)NPG) {
            int pos = atomicAdd(&cur[c], 1);
            src1p[(c << 6) + pos] = (u16)ed1[e];
        }
    }
    for (int e = tid; e < EE; e += nthr) {
        int c = ed2[e + EE];
        if ((u32)(c - lo) < (u32)NPG) {
            int pos = atomicAdd(&cur[NN + c], 1);
            src2p[(c << 6) + pos] = (u16)ed2[e];
        }
    }
}

__global__ void k_dinv2(const int* __restrict__ deg, float* __restrict__ dinv1,
                        float* __restrict__ dinv2, int n) {
    int v = blockIdx.x * blockDim.x + threadIdx.x;
    if (v >= 2 * n) return;
    float* d = (v < n) ? dinv1 : dinv2;
    int vv = (v < n) ? v : v - n;
    d[vv] = rsqrtf((float)(deg[v] + 1));  // +1 self-loop
}

// ---------------- weight transpose + bf16 cast: W[K][N] f32 -> Wt[N][K] bf16 ----------------
__global__ void k_wt(const float* __restrict__ W, u16* __restrict__ Wt, int K, int N) {
    __shared__ u16 sm[32][33];
    const float* Wl = W + (size_t)blockIdx.z * K * N;
    u16* Wtl = Wt + (size_t)blockIdx.z * K * N;
    int k0 = blockIdx.y * 32, n0 = blockIdx.x * 32;
    int tx = threadIdx.x, ty = threadIdx.y;  // 32 x 8
#pragma unroll
    for (int r = 0; r < 32; r += 8)
        sm[ty + r][tx] = f2bf(Wl[(size_t)(k0 + ty + r) * N + n0 + tx]);
    __syncthreads();
#pragma unroll
    for (int r = 0; r < 32; r += 8)
        Wtl[(size_t)(n0 + ty + r) * K + k0 + tx] = sm[tx][ty + r];
}

// outW [H=256][C=112] f32 -> outWt [128][256] bf16 (rows >= C zero); pad bias to 128
__global__ void k_outwt(const float* __restrict__ outW, const float* __restrict__ outb,
                        u16* __restrict__ outWt, float* __restrict__ obb) {
    int idx = blockIdx.x * 256 + threadIdx.x;     // 128*256
    if (idx >= 128 * 256) return;
    int n = idx >> 8, k = idx & 255;
    float v = (n < CC) ? outW[(size_t)k * CC + n] : 0.f;
    outWt[(size_t)n * HH + k] = f2bf(v);
    if (idx < 128) obb[idx] = (idx < CC) ? outb[idx] : 0.f;
}

// ---------------- fp32 -> bf16 cast ----------------
__global__ void k_xcast(const float* __restrict__ x, u16* __restrict__ xb, int n4) {
    int i = blockIdx.x * blockDim.x + threadIdx.x;
    if (i >= n4) return;
    float4 v = ((const float4*)x)[i];
    ushort4 o;
    o.x = f2bf(v.x); o.y = f2bf(v.y); o.z = f2bf(v.z); o.w = f2bf(v.w);
    *(ushort4*)(xb + ((size_t)i << 2)) = o;
}

// ---- bf16 MFMA GEMM: C = A @ Bt^T + bias, per-row scale; XCD-aware m/n swizzle when SWIZ ---
// SLICED: store u16 C in column-sliced layout [Nc/32][M][32] for the L2-pinned spmm gather.
template <bool F32OUT, bool SWIZ, bool SLICED>
__global__ __launch_bounds__(256) void k_gemm_bf16(const u16* __restrict__ A,
                                                   const u16* __restrict__ Bt,
                                                   const float* __restrict__ bias,
                                                   const float* __restrict__ rowscale,
                                                   void* __restrict__ Cout,
                                                   int M, int Nc, int K) {
    int m0, n0;
    if (SWIZ) {
        int id = blockIdx.x;
        int g = id >> 4, r = id & 15;
        int m = g * 8 + (r & 7);
        if (m * 128 >= M) return;
        m0 = m * 128;
        n0 = (r >> 3) * 128;
    } else {
        m0 = blockIdx.x * 128;
        n0 = 0;
    }
    __shared__ u16 As[128 * 32];
    __shared__ u16 Bs[128 * 32];
    const int tid = threadIdx.x;
    const int w = tid >> 6, lane = tid & 63;
    const int wr = (w >> 1) * 64, wc = (w & 1) * 64;
    const int lm = lane & 15, lq = lane >> 4;

    f32x4 acc[4][4];
#pragma unroll
    for (int i = 0; i < 4; ++i)
#pragma unroll
        for (int j = 0; j < 4; ++j) acc[i][j] = (f32x4){0.f, 0.f, 0.f, 0.f};

    const int srow = w * 16 + (lane >> 2);
    const int scol = (lane & 3) * 8;

    for (int k0 = 0; k0 < K; k0 += 32) {
        int gm = m0 + srow;        if (gm >= M) gm = M - 1;
        gload16(A + (size_t)gm * K + k0 + scol, As + (size_t)(w * 64) * 8);
        int gm2 = m0 + 64 + srow;  if (gm2 >= M) gm2 = M - 1;
        gload16(A + (size_t)gm2 * K + k0 + scol, As + (size_t)(256 + w * 64) * 8);
        gload16(Bt + (size_t)(n0 + srow) * K + k0 + scol, Bs + (size_t)(w * 64) * 8);
        gload16(Bt + (size_t)(n0 + 64 + srow) * K + k0 + scol, Bs + (size_t)(256 + w * 64) * 8);
        __syncthreads();

        bf16x8 af[4], bfr[4];
#pragma unroll
        for (int i = 0; i < 4; ++i)
            af[i] = *(const bf16x8*)(As + (wr + i * 16 + lm) * 32 + lq * 8);
#pragma unroll
        for (int j = 0; j < 4; ++j)
            bfr[j] = *(const bf16x8*)(Bs + (wc + j * 16 + lm) * 32 + lq * 8);
#pragma unroll
        for (int i = 0; i < 4; ++i)
#pragma unroll
            for (int j = 0; j < 4; ++j)
                acc[i][j] = __builtin_amdgcn_mfma_f32_16x16x32_bf16(af[i], bfr[j], acc[i][j], 0, 0, 0);
        __syncthreads();
    }

    // epilogue: C/D layout col=lane&15, row=(lane>>4)*4+reg  [m89-verified]
#pragma unroll
    for (int j = 0; j < 4; ++j) {
        int gc = n0 + wc + j * 16 + lm;
        float bj = (gc < Nc) ? bias[gc] : 0.f;
#pragma unroll
        for (int i = 0; i < 4; ++i) {
#pragma unroll
            for (int r = 0; r < 4; ++r) {
                int gr = m0 + wr + i * 16 + lq * 4 + r;
                if (gr < M && gc < Nc) {
                    float rs = rowscale ? rowscale[gr] : 1.0f;
                    float val = (acc[i][j][r] + bj) * rs;
                    if (F32OUT)
                        ((float*)Cout)[(size_t)gr * Nc + gc] = val;
                    else if (SLICED)
                        ((u16*)Cout)[((size_t)(gc >> 5) * M + gr) * SLW + (gc & 31)] = f2bf(val);
                    else
                        ((u16*)Cout)[(size_t)gr * Nc + gc] = f2bf(val);
                }
            }
        }
    }
}

#define ACC8(b) { A[0] += bflo(b.x); A[1] += bfhi(b.x); A[2] += bflo(b.y); A[3] += bfhi(b.y); \
                  A[4] += bflo(b.z); A[5] += bfhi(b.z); A[6] += bflo(b.w); A[7] += bfhi(b.w); }

// -- column-sliced gather SpMM, 4-LANE row-subgroups (uint4 = 16 B/lane) + fused BN stats ----
// slice = blockIdx & 7 -> pinned to one XCD (grid 3128 % 8 == 0); 3.2 MB L2-resident slice.
// Round-10 diagnosis: spmm is TA/address-throughput bound (~16 cy per divergent wave-instr;
// 8-lane floor 48 us x 1.4 divergence = 67 us matches all 3 prior variants). Halve the
// instruction count: 4 lanes x uint4 cover the 64 B row -> 16 nodes/wave, 16 lines/instr,
// 1024 B/instr. Floor ~24 us x 1.65 (E[max of 16 Poisson(16)]/16) ~ 45 us.
__global__ __launch_bounds__(512) void k_spmm_sl4(const u16* __restrict__ ts,
                                                  const int* __restrict__ deg,
                                                  const u16* __restrict__ srcp,
                                                  const float* __restrict__ dinv,
                                                  u16* __restrict__ hpre,
                                                  float* __restrict__ bns,   // [8][HH]
                                                  float* __restrict__ bnq) { // [8][HH]
    __shared__ float lsum[8][SLW];
    __shared__ float lsq[8][SLW];
    const int s = blockIdx.x & 7;
    const int nb = blockIdx.x >> 3;
    const int w = threadIdx.x >> 6;
    const int lane = threadIdx.x & 63;
    const int sub = lane >> 2;          // node subgroup 0..15
    const int li = lane & 3;            // lane covers cols 8li..8li+7 of the slice (uint4)
    const u16* tsl = ts + (size_t)s * NN * SLW + li * 8;

    const int v = nb * 128 + w * 16 + sub;
    float ss[8], qq[8];
#pragma unroll
    for (int k = 0; k < 8; ++k) { ss[k] = 0.f; qq[k] = 0.f; }

    if (v < NN) {
        const u16* src = srcp + ((size_t)v << 6);
        const float dv = dinv[v];
        uint4 a = *(const uint4*)(tsl + (size_t)v * SLW);
        float A[8];
        A[0] = bflo(a.x); A[1] = bfhi(a.x); A[2] = bflo(a.y); A[3] = bfhi(a.y);
        A[4] = bflo(a.z); A[5] = bfhi(a.z); A[6] = bflo(a.w); A[7] = bfhi(a.w);
        int end = deg[v];
        int j = 0;
        for (; j + 8 <= end; j += 8) {
            uint4 sp = *(const uint4*)(src + j);   // 8 packed u16 indices (subgroup-bcast)
            uint4 b0 = *(const uint4*)(tsl + (size_t)(sp.x & 0xFFFFu) * SLW);
            uint4 b1 = *(const uint4*)(tsl + (size_t)(sp.x >> 16) * SLW);
            uint4 b2 = *(const uint4*)(tsl + (size_t)(sp.y & 0xFFFFu) * SLW);
            uint4 b3 = *(const uint4*)(tsl + (size_t)(sp.y >> 16) * SLW);
            uint4 b4 = *(const uint4*)(tsl + (size_t)(sp.z & 0xFFFFu) * SLW);
            uint4 b5 = *(const uint4*)(tsl + (size_t)(sp.z >> 16) * SLW);
            uint4 b6 = *(const uint4*)(tsl + (size_t)(sp.w & 0xFFFFu) * SLW);
            uint4 b7 = *(const uint4*)(tsl + (size_t)(sp.w >> 16) * SLW);
            ACC8(b0); ACC8(b1); ACC8(b2); ACC8(b3);
            ACC8(b4); ACC8(b5); ACC8(b6); ACC8(b7);
        }
        for (; j + 2 <= end; j += 2) {
            int s0 = src[j], s1 = src[j + 1];
            uint4 b0 = *(const uint4*)(tsl + (size_t)s0 * SLW);
            uint4 b1 = *(const uint4*)(tsl + (size_t)s1 * SLW);
            ACC8(b0); ACC8(b1);
        }
        if (j < end) {
            uint4 b0 = *(const uint4*)(tsl + (size_t)src[j] * SLW);
            ACC8(b0);
        }
        u32 p01 = (u32)f2bf(A[0] * dv) | ((u32)f2bf(A[1] * dv) << 16);
        u32 p23 = (u32)f2bf(A[2] * dv) | ((u32)f2bf(A[3] * dv) << 16);
        u32 p45 = (u32)f2bf(A[4] * dv) | ((u32)f2bf(A[5] * dv) << 16);
        u32 p67 = (u32)f2bf(A[6] * dv) | ((u32)f2bf(A[7] * dv) << 16);
        uint4 ov; ov.x = p01; ov.y = p23; ov.z = p45; ov.w = p67;
        *(uint4*)(hpre + (size_t)v * HH + s * SLW + li * 8) = ov;
        ss[0] = bflo(p01); ss[1] = bfhi(p01); ss[2] = bflo(p23); ss[3] = bfhi(p23);
        ss[4] = bflo(p45); ss[5] = bfhi(p45); ss[6] = bflo(p67); ss[7] = bfhi(p67);
#pragma unroll
        for (int k = 0; k < 8; ++k) qq[k] = ss[k] * ss[k];
    }

    // reduce over the wave's 16 subgroups (lanes differing in bits 2..5)
#pragma unroll
    for (int d = 4; d < 64; d <<= 1) {
#pragma unroll
        for (int k = 0; k < 8; ++k) {
            ss[k] += __shfl_xor(ss[k], d, 64);
            qq[k] += __shfl_xor(qq[k], d, 64);
        }
    }
    if (lane < 4) {
#pragma unroll
        for (int k = 0; k < 8; ++k) { lsum[w][li * 8 + k] = ss[k]; lsq[w][li * 8 + k] = qq[k]; }
    }
    __syncthreads();
    int t = threadIdx.x;
    if (t < SLW) {
        float a = 0.f;
#pragma unroll
        for (int ww = 0; ww < 8; ++ww) a += lsum[ww][t];
        atomicAdd(&bns[(nb & 7) * HH + s * SLW + t], a);
    } else if (t < 2 * SLW) {
        int c = t - SLW;
        float a = 0.f;
#pragma unroll
        for (int ww = 0; ww < 8; ++ww) a += lsq[ww][c];
        atomicAdd(&bnq[(nb & 7) * HH + s * SLW + c], a);
    }
}

// ---- normalize + ReLU + weighted residual; bins folded once per block into LDS scale/shift -
__global__ __launch_bounds__(256) void k_bnnorm(const u16* __restrict__ hpre,
                         u16* __restrict__ accb, u16* __restrict__ hb,
                         const float* __restrict__ bins,   // [16][HH]: 8 sum + 8 sq
                         const float* __restrict__ gamma, const float* __restrict__ beta,
                         const float* __restrict__ wArr, int layer) {
    __shared__ float sscale[HH], sshift[HH];
    const float invN = 1.0f / (float)NN;
    {
        int tcol = threadIdx.x;
        float m = 0.f, qq = 0.f;
#pragma unroll
        for (int b = 0; b < 8; ++b) {
            m += bins[b * HH + tcol];
            qq += bins[(8 + b) * HH + tcol];
        }
        m *= invN;
        float var = qq * invN - m * m;
        float sc = rsqrtf(var + EPSB) * gamma[tcol];
        sscale[tcol] = sc;
        sshift[tcol] = beta[tcol] - m * sc;
    }
    __syncthreads();
    int idx = blockIdx.x * blockDim.x + threadIdx.x;
    if (idx >= NN * (HH / 4)) return;
    int c = (idx & 63) << 2;
    float w = wArr[layer];
    ushort4 hv = ((const ushort4*)hpre)[idx];
    ushort4 av = ((const ushort4*)accb)[idx];
    u16* hp = &hv.x;
    u16* ap = &av.x;
    ushort4 oh, oa;
    u16* ohp = &oh.x;
    u16* oap = &oa.x;
#pragma unroll
    for (int k = 0; k < 4; ++k) {
        float v = fmaf(bf1(hp[k]), sscale[c + k], sshift[c + k]);
        v = fmaxf(v, 0.f);
        oap[k] = f2bf(fmaf(w, v, bf1(ap[k])));
        ohp[k] = f2bf(v);
    }
    ((ushort4*)accb)[idx] = oa;
    *(ushort4*)(hb + ((size_t)idx << 2)) = oh;
}

// ---------------- softmax of the 8 layer weights ----------------
__global__ void k_softmaxw(const float* __restrict__ lw, float* __restrict__ wArr) {
    if (threadIdx.x == 0 && blockIdx.x == 0) {
        float m = -3.0e38f;
        for (int i = 0; i < LL; ++i) m = fmaxf(m, lw[i]);
        float e[LL]; float sum = 0.f;
        for (int i = 0; i < LL; ++i) { e[i] = expf(lw[i] - m); sum += e[i]; }
        for (int i = 0; i < LL; ++i) wArr[i] = e[i] / sum;
    }
}

// ---------------- log_softmax rows ----------------
__global__ __launch_bounds__(256) void k_logsoftmax(const float* __restrict__ z,
                                                    float* __restrict__ out) {
    int gt = blockIdx.x * blockDim.x + threadIdx.x;
    int v = gt >> 6;
    int lane = threadIdx.x & 63;
    if (v >= NN) return;
    const float* row = z + (size_t)v * CC;
    float v0 = row[lane];
    float v1 = (lane + 64 < CC) ? row[lane + 64] : -3.0e38f;
    float m = fmaxf(v0, v1);
#pragma unroll
    for (int d = 1; d < 64; d <<= 1) m = fmaxf(m, __shfl_xor(m, d, 64));
    float e = expf(v0 - m) + ((lane + 64 < CC) ? expf(v1 - m) : 0.f);
#pragma unroll
    for (int d = 1; d < 64; d <<= 1) e += __shfl_xor(e, d, 64);
    float lse = m + logf(e);
    out[(size_t)v * CC + lane] = v0 - lse;
    if (lane + 64 < CC) out[(size_t)v * CC + lane + 64] = v1 - lse;
}

extern "C" void kernel_launch(void* const* d_in, const int* in_sizes, int n_in,
                              void* d_out, int out_size, void* d_ws, size_t ws_size,
                              hipStream_t stream) {
    const float* x     = (const float*)d_in[0];
    const int*   e1    = (const int*)d_in[1];
    const int*   e2    = (const int*)d_in[2];
    const float* inW   = (const float*)d_in[3];
    const float* inb   = (const float*)d_in[4];
    const float* convW = (const float*)d_in[5];
    const float* convB = (const float*)d_in[6];
    const float* gamma = (const float*)d_in[7];
    const float* beta  = (const float*)d_in[8];
    const float* outW  = (const float*)d_in[9];
    const float* outb  = (const float*)d_in[10];
    const float* lw    = (const float*)d_in[11];

    char* ws = (char*)d_ws;
    size_t off = 0;
    auto alloc = [&](size_t bytes) -> void* {
        void* p = ws + off;
        off = (off + bytes + 255) & ~(size_t)255;
        return p;
    };
    u16*   hb    = (u16*)alloc((size_t)NN * HH * 2);     // bf16 h (GEMM A)
    u16*   tb    = (u16*)alloc((size_t)NN * HH * 2);     // bf16 t' SLICED [8][NN][32]; alias xb
    u16*   hpre  = (u16*)alloc((size_t)NN * HH * 2);     // spmm out; alias logits(f32)
    u16*   accb  = (u16*)alloc((size_t)NN * HH * 2);     // bf16 residual accumulator
    u16*   convWt= (u16*)alloc((size_t)LL * HH * HH * 2);
    u16*   inWt  = (u16*)alloc((size_t)HH * FIN * 2);
    u16*   outWt = (u16*)alloc((size_t)128 * HH * 2);
    float* obb   = (float*)alloc(128 * 4);
    float* dinv1 = (float*)alloc((size_t)NN * 4);
    float* dinv2 = (float*)alloc((size_t)NN * 4);
    u16*   src1p = (u16*)alloc((size_t)NN * 64 * 2);     // padded CSR, 64 u16 slots/node
    u16*   src2p = (u16*)alloc((size_t)NN * 64 * 2);
    int*   curz  = (int*)alloc((size_t)2 * NN * 4);      // cur1,cur2 (degree counters)
    float* bnsq  = (float*)alloc((size_t)LL * 16 * HH * 4);  // per layer: 8 sum + 8 sq bins
    float* wArr  = (float*)alloc(64);
    u16*   xb    = tb;            // x_bf16 dead once layer-0 conv GEMM writes tb
    float* logits = (float*)hpre; // fp32 logits: hpre free after last bnnorm

    int* cur1 = curz;

    hipMemsetAsync(curz, 0, (size_t)2 * NN * 4, stream);
    hipMemsetAsync(bnsq, 0, (size_t)LL * 16 * HH * 4, stream);
    hipMemsetAsync(accb, 0, (size_t)NN * HH * 2, stream);

    // padded CSR build: XCD-partitioned (8 groups x 256 blocks), u16 slots
    k_fill2<<<8 * 256, 256, 0, stream>>>(e1, e2, curz, src1p, src2p);
    k_dinv2<<<(2 * NN + 255) / 256, 256, 0, stream>>>(curz, dinv1, dinv2, NN);

    k_softmaxw<<<1, 64, 0, stream>>>(lw, wArr);

    // weight prep
    {
        dim3 g(HH / 32, HH / 32, LL);
        dim3 b(32, 8);
        k_wt<<<g, b, 0, stream>>>(convW, convWt, HH, HH);
        dim3 g2(HH / 32, FIN / 32, 1);
        k_wt<<<g2, b, 0, stream>>>(inW, inWt, FIN, HH);
        k_outwt<<<128, 256, 0, stream>>>(outW, outb, outWt, obb);
    }
    k_xcast<<<(NN * FIN / 4 + 255) / 256, 256, 0, stream>>>(x, xb, NN * FIN / 4);

    const int MT = (NN + 127) / 128;               // 391
    const int GSW = ((MT + 7) / 8) * 16;           // swizzled grid: 784
    // input FC: hb = bf16( x @ inW + inb )   (standard layout: next GEMM's A)
    k_gemm_bf16<false, true, false><<<GSW, 256, 0, stream>>>(xb, inWt, inb, nullptr, hb,
                                                             NN, HH, FIN);

    const int NBL = (NN + 127) / 128;              // 391 node-blocks (128 nodes each)
    const int SPB = NBL * NSL;                     // 391 x 8 slices = 3128 (% 8 == 0)
    const int ELB = (NN * (HH / 4) + 255) / 256;
    for (int i = 0; i < LL; ++i) {
        const int* dg = (i < LL / 2) ? cur1 : (curz + NN);
        const u16* sr = (i < LL / 2) ? src1p : src2p;
        const float* dv = (i < LL / 2) ? dinv1 : dinv2;
        float* bins = bnsq + (size_t)i * 16 * HH;
        // tb = bf16( dinv[r] * (hb @ convW_i + convB_i) )  in SLICED layout
        k_gemm_bf16<false, true, true><<<GSW, 256, 0, stream>>>(hb,
                                                          convWt + (size_t)i * HH * HH,
                                                          convB + (size_t)i * HH, dv, tb,
                                                          NN, HH, HH);
        k_spmm_sl4<<<SPB, 512, 0, stream>>>(tb, dg, sr, dv, hpre, bins, bins + 8 * HH);
        k_bnnorm<<<ELB, 256, 0, stream>>>(hpre, accb, hb, bins,
                                          gamma + (size_t)i * HH, beta + (size_t)i * HH,
                                          wArr, i);
    }

    // out FC: logits = accb @ outWt^T + obb   (fp32 store into hpre, Nc=112, single n-tile)
    k_gemm_bf16<true, false, false><<<MT, 256, 0, stream>>>(accb, outWt, obb, nullptr, logits,
                                                            NN, CC, HH);
    k_logsoftmax<<<NN / 4, 256, 0, stream>>>(logits, (float*)d_out);
}